// Round 3
// baseline (2326.357 us; speedup 1.0000x reference)
//
#include <hip/hip_runtime.h>

typedef __attribute__((ext_vector_type(8))) __bf16 bf16x8;
typedef __attribute__((ext_vector_type(4))) __bf16 bf16x4;
typedef __attribute__((ext_vector_type(4))) float f32x4;
typedef __attribute__((ext_vector_type(4))) unsigned short u16x4;

#define AS1 __attribute__((address_space(1)))
#define AS3 __attribute__((address_space(3)))

__device__ __forceinline__ void ld_g2l16(const __bf16* g, __bf16* l) {
    // 16B/lane direct global->LDS (guide m97). LDS dest is wave-uniform base.
    __builtin_amdgcn_global_load_lds((AS1 void*)g, (AS3 void*)l, 16, 0, 0);
}

// ---------------------------------------------------------------------------
// C[m,n] = sum_k A[m,k]*B[n,k] (+ bias[n])   (A:[M,K], B:[N,K], both bf16)
// MODE 0: bf16 store + bias (LDS-repacked 16B stores)
// MODE 1: xv = Cf+acc+bias; Cf=xv fp32; Cb=bf16(xv)   (residual epilogue)
// MODE 2: bf16 store, no bias
// Batched over blockIdx.z via element strides sA/sB/sBias/sC.
// 128x128 tile, BK=64, 4 waves 2x2, each wave 4x4 of 16x16x32 MFMA tiles.
// ---------------------------------------------------------------------------
template<int MODE>
__global__ void gemm_bt(const __bf16* __restrict__ A, const __bf16* __restrict__ B,
                        const float* __restrict__ bias, __bf16* __restrict__ Cb,
                        float* __restrict__ Cf, int M, int N, int K,
                        size_t sA, size_t sB, size_t sBias, size_t sC)
{
    __shared__ __align__(16) __bf16 smem[17408];  // staging 2*128*64; epi tile 128x136
    const int z = blockIdx.z;
    A += (size_t)z * sA;  B += (size_t)z * sB;  Cb += (size_t)z * sC;
    if (MODE != 2) bias += (size_t)z * sBias;
    if (MODE == 1) Cf += (size_t)z * sC;

    __bf16* As = smem;
    __bf16* Bs = smem + 128 * 64;
    const int tid = threadIdx.x;
    const int wave = tid >> 6, lane = tid & 63;
    const int quad = lane >> 4, l15 = lane & 15;
    const int lrow = lane >> 3, lcol = lane & 7;
    const int m0 = blockIdx.y * 128, n0 = blockIdx.x * 128;
    const int wm = wave & 1, wn = wave >> 1;
    const __bf16* Ab = A + (size_t)m0 * K;
    const __bf16* Bb = B + (size_t)n0 * K;

    f32x4 acc[4][4] = {};

    for (int k0 = 0; k0 < K; k0 += 64) {
        __syncthreads();
        #pragma unroll
        for (int j = 0; j < 4; ++j) {
            const int chunk = wave * 4 + j;          // 16 chunks of 8 rows
            const int row = chunk * 8 + lrow;
            ld_g2l16(Ab + (size_t)row * K + k0 + lcol * 8, &As[chunk * 512]);
            ld_g2l16(Bb + (size_t)row * K + k0 + lcol * 8, &Bs[chunk * 512]);
        }
        __syncthreads();
        #pragma unroll
        for (int s = 0; s < 2; ++s) {
            bf16x8 af[4], bfr[4];
            #pragma unroll
            for (int r = 0; r < 4; ++r)
                af[r] = *(const bf16x8*)&As[(wm * 64 + r * 16 + l15) * 64 + s * 32 + quad * 8];
            #pragma unroll
            for (int c = 0; c < 4; ++c)
                bfr[c] = *(const bf16x8*)&Bs[(wn * 64 + c * 16 + l15) * 64 + s * 32 + quad * 8];
            #pragma unroll
            for (int r = 0; r < 4; ++r)
                #pragma unroll
                for (int c = 0; c < 4; ++c)
                    acc[r][c] = __builtin_amdgcn_mfma_f32_16x16x32_bf16(af[r], bfr[c], acc[r][c], 0, 0, 0);
        }
    }

    // C/D layout (measured m89/m91): col = lane&15, row = quad*4 + reg
    if (MODE != 1) {
        __syncthreads();
        __bf16 (*Cs)[136] = (__bf16(*)[136])smem;
        #pragma unroll
        for (int r = 0; r < 4; ++r)
            #pragma unroll
            for (int c = 0; c < 4; ++c) {
                const float bv = (MODE == 0) ? bias[n0 + wn * 64 + c * 16 + l15] : 0.0f;
                #pragma unroll
                for (int e = 0; e < 4; ++e)
                    Cs[wm * 64 + r * 16 + quad * 4 + e][wn * 64 + c * 16 + l15] =
                        (__bf16)(acc[r][c][e] + bv);
            }
        __syncthreads();
        #pragma unroll
        for (int p = 0; p < 8; ++p) {
            const int i = p * 256 + tid;      // 2048 chunks of 16B
            const int row = i >> 4, ch = i & 15;
            *(bf16x8*)&Cb[(size_t)(m0 + row) * N + n0 + ch * 8] =
                *(const bf16x8*)&Cs[row][ch * 8];
        }
    } else {
        #pragma unroll
        for (int r = 0; r < 4; ++r)
            #pragma unroll
            for (int c = 0; c < 4; ++c)
                #pragma unroll
                for (int e = 0; e < 4; ++e) {
                    const int m = m0 + wm * 64 + r * 16 + quad * 4 + e;
                    const int n = n0 + wn * 64 + c * 16 + l15;
                    const float v = acc[r][c][e] + bias[n];
                    const size_t idx = (size_t)m * N + n;
                    const float xv = Cf[idx] + v;
                    Cf[idx] = xv;
                    Cb[idx] = (__bf16)xv;
                }
    }
}

// ---------------------------------------------------------------------------
// s_partial: P[ch][bh][d1*64+d2] = sum_{t in chunk} K[t,d1]*V[t,d2]  (fp32)
// kv layout: [b,t, d(2048)] with K at d<1024, V at d>=1024.
// ---------------------------------------------------------------------------
__global__ void s_partial(const __bf16* __restrict__ kv, float* __restrict__ P)
{
    constexpr int CH = 128;
    __shared__ __align__(16) __bf16 Kt[64][CH + 8];
    __shared__ __align__(16) __bf16 Vt[64][CH + 8];
    const int bh = blockIdx.x, chb = blockIdx.y;
    const int b = bh >> 4, h = bh & 15;
    const int t0 = chb * CH;
    const int tid = threadIdx.x;
    const int wave = tid >> 6, lane = tid & 63;
    const int quad = lane >> 4, l15 = lane & 15;
    const __bf16* Kbase = kv + (size_t)b * 2048 * 2048 + h * 64;
    const __bf16* Vbase = Kbase + 1024;

    for (int i = tid; i < CH * 16; i += 256) {
        const int t = i >> 4, d4 = (i & 15) * 4;
        union { u16x4 u; __bf16 b[4]; } kvv, vv;
        kvv.u = *(const u16x4*)(Kbase + (size_t)(t0 + t) * 2048 + d4);
        vv.u  = *(const u16x4*)(Vbase + (size_t)(t0 + t) * 2048 + d4);
        #pragma unroll
        for (int j = 0; j < 4; ++j) {
            Kt[d4 + j][t] = kvv.b[j];
            Vt[d4 + j][t] = vv.b[j];
        }
    }
    __syncthreads();

    f32x4 acc[4] = {};
    #pragma unroll
    for (int s = 0; s < CH / 32; ++s) {
        const bf16x8 a = *(const bf16x8*)&Kt[wave * 16 + l15][s * 32 + quad * 8];  // m = d1
        #pragma unroll
        for (int c = 0; c < 4; ++c) {
            const bf16x8 bb = *(const bf16x8*)&Vt[c * 16 + l15][s * 32 + quad * 8]; // n = d2
            acc[c] = __builtin_amdgcn_mfma_f32_16x16x32_bf16(a, bb, acc[c], 0, 0, 0);
        }
    }

    // store [d1][d2]: row = d1 = wave*16+quad*4+e, col = d2 = c*16+l15
    float* Pb = P + ((size_t)chb * 64 + bh) * 4096;
    #pragma unroll
    for (int c = 0; c < 4; ++c)
        #pragma unroll
        for (int e = 0; e < 4; ++e)
            Pb[(size_t)(wave * 16 + quad * 4 + e) * 64 + c * 16 + l15] = acc[c][e];
}

// s_reduce: S2[bh][d1][d2] = 0.125 * sum_ch P[ch][bh][d1][d2]   (bf16)
__global__ void s_reduce(const float* __restrict__ P, __bf16* __restrict__ S2)
{
    const int g = blockIdx.x * 256 + threadIdx.x;   // vec4 index, 65536 total
    f32x4 s = {};
    #pragma unroll
    for (int ch = 0; ch < 16; ++ch)
        s += *(const f32x4*)&P[(size_t)ch * 262144 + (size_t)g * 4];
    bf16x4 o;
    #pragma unroll
    for (int e = 0; e < 4; ++e) o[e] = (__bf16)(s[e] * 0.125f);
    *(bf16x4*)&S2[(size_t)g * 4] = o;
}

// ---------------------------------------------------------------------------
// wfold: Wf[b][n][h*64+d1] = sum_d2 Wproj[n, h*64+d2] * S2[bh][d1][d2]
// One block per (b,h). 4 waves stride over 1024 n-rows in 16-row tiles.
// ---------------------------------------------------------------------------
__global__ void wfold(const __bf16* __restrict__ Wp, const __bf16* __restrict__ S2,
                      __bf16* __restrict__ Wf)
{
    const int bh = blockIdx.x, b = bh >> 4, h = bh & 15;
    const int tid = threadIdx.x;
    const int wave = tid >> 6, lane = tid & 63;
    const int quad = lane >> 4, l15 = lane & 15;
    const __bf16* Sb = S2 + (size_t)bh * 4096;

    bf16x8 bfr[4][2];
    #pragma unroll
    for (int d1t = 0; d1t < 4; ++d1t)
        #pragma unroll
        for (int s = 0; s < 2; ++s)
            bfr[d1t][s] = *(const bf16x8*)&Sb[(size_t)(d1t * 16 + l15) * 64 + s * 32 + quad * 8];

    __bf16* out = Wf + (size_t)b * 1048576 + h * 64;
    for (int mt = 0; mt < 16; ++mt) {
        const int row0 = (mt * 4 + wave) * 16;
        bf16x8 af[2];
        #pragma unroll
        for (int s = 0; s < 2; ++s)
            af[s] = *(const bf16x8*)&Wp[(size_t)(row0 + l15) * 1024 + h * 64 + s * 32 + quad * 8];
        f32x4 acc[4] = {};
        #pragma unroll
        for (int d1t = 0; d1t < 4; ++d1t)
            #pragma unroll
            for (int s = 0; s < 2; ++s)
                acc[d1t] = __builtin_amdgcn_mfma_f32_16x16x32_bf16(af[s], bfr[d1t][s], acc[d1t], 0, 0, 0);
        #pragma unroll
        for (int d1t = 0; d1t < 4; ++d1t)
            #pragma unroll
            for (int e = 0; e < 4; ++e)
                out[(size_t)(row0 + quad * 4 + e) * 1024 + d1t * 16 + l15] = (__bf16)acc[d1t][e];
    }
}

// rvec: r[b][n] = bproj[n] + sum_k bq[k] * Wf[b][n][k]
__global__ void rvec(const float* __restrict__ bq, const float* __restrict__ bproj,
                     const __bf16* __restrict__ Wf, float* __restrict__ r)
{
    const int n = blockIdx.x * 128 + threadIdx.x;
    const int b = blockIdx.y;
    const __bf16* row = Wf + (size_t)b * 1048576 + (size_t)n * 1024;
    float s = bproj[n];
    for (int kc = 0; kc < 128; ++kc) {
        const bf16x8 w = *(const bf16x8*)&row[kc * 8];
        #pragma unroll
        for (int j = 0; j < 8; ++j) s += bq[kc * 8 + j] * (float)w[j];
    }
    r[b * 1024 + n] = s;
}

// ---------------------------------------------------------------------------
__global__ void cvt_bf16(const float* __restrict__ src, __bf16* __restrict__ dst, int n4)
{
    const int i = blockIdx.x * 256 + threadIdx.x;
    if (i >= n4) return;
    const float4 v = ((const float4*)src)[i];
    bf16x4 o = { (__bf16)v.x, (__bf16)v.y, (__bf16)v.z, (__bf16)v.w };
    ((bf16x4*)dst)[i] = o;
}

// KV slice of Wqkv (rows 1024..3071 per layer) -> contiguous bf16 [12][2048][1024]
__global__ void cvt_kv(const float* __restrict__ Wqkv, __bf16* __restrict__ dst)
{
    const unsigned i = blockIdx.x * 256 + threadIdx.x;      // vec4 idx, 6291456 total
    const unsigned layer = i >> 19;                          // / 524288
    const unsigned w = i & 524287;
    const float4 v = ((const float4*)Wqkv)[(size_t)layer * 786432 + 262144 + w];
    bf16x4 o = { (__bf16)v.x, (__bf16)v.y, (__bf16)v.z, (__bf16)v.w };
    ((bf16x4*)dst)[i] = o;
}

// WqT[L][c][k] = bf16(Wqkv[L][k][c]), k<1024 (Q rows). 64x64 tiles via LDS.
__global__ void wq_transpose(const float* __restrict__ Wqkv, __bf16* __restrict__ WqT)
{
    __shared__ __bf16 T[64][72];
    const int k0 = blockIdx.x * 64, c0 = blockIdx.y * 64, L = blockIdx.z;
    const float* src = Wqkv + (size_t)L * 3145728;
    const int tid = threadIdx.x;
    const int r = tid >> 2, cq = (tid & 3) * 16;
    #pragma unroll
    for (int j = 0; j < 4; ++j) {
        const float4 f = *(const float4*)&src[(size_t)(k0 + r) * 1024 + c0 + cq + j * 4];
        T[cq + j * 4 + 0][r] = (__bf16)f.x;
        T[cq + j * 4 + 1][r] = (__bf16)f.y;
        T[cq + j * 4 + 2][r] = (__bf16)f.z;
        T[cq + j * 4 + 3][r] = (__bf16)f.w;
    }
    __syncthreads();
    __bf16* dst = WqT + (size_t)L * 1048576;
    #pragma unroll
    for (int j = 0; j < 2; ++j)
        *(bf16x8*)&dst[(size_t)(c0 + r) * 1024 + k0 + cq + j * 8] = *(const bf16x8*)&T[r][cq + j * 8];
}

__global__ void init_x(const float* __restrict__ src, __bf16* __restrict__ xB,
                       float* __restrict__ xF, int n4)
{
    const int i = blockIdx.x * 256 + threadIdx.x;
    if (i >= n4) return;
    const float4 v = ((const float4*)src)[i];
    ((float4*)xF)[i] = v;
    bf16x4 o = { (__bf16)v.x, (__bf16)v.y, (__bf16)v.z, (__bf16)v.w };
    ((bf16x4*)xB)[i] = o;
}

// ---------------------------------------------------------------------------
extern "C" void kernel_launch(void* const* d_in, const int* in_sizes, int n_in,
                              void* d_out, int out_size, void* d_ws, size_t ws_size,
                              hipStream_t stream)
{
    const float* x0    = (const float*)d_in[0];   // [4,2048,1024]
    const float* Wqkv  = (const float*)d_in[1];   // [12,3072,1024]
    const float* bqkv  = (const float*)d_in[2];   // [12,3072]
    const float* Wproj = (const float*)d_in[3];   // [12,1024,1024]
    const float* bproj = (const float*)d_in[4];   // [12,1024]
    float* xF = (float*)d_out;                    // fp32 x master lives in d_out

    char* p = (char*)d_ws;
    __bf16* WkvB   = (__bf16*)p; p += (size_t)12 * 2048 * 1024 * 2;  // 50.3 MB
    __bf16* WprojB = (__bf16*)p; p += (size_t)12 * 1024 * 1024 * 2;  // 25.2 MB
    __bf16* WqT    = (__bf16*)p; p += (size_t)12 * 1024 * 1024 * 2;  // 25.2 MB
    __bf16* xPing  = (__bf16*)p; p += (size_t)8192 * 1024 * 2;       // 16.8 MB
    __bf16* xPong  = (__bf16*)p; p += (size_t)8192 * 1024 * 2;       // 16.8 MB
    __bf16* kv     = (__bf16*)p; p += (size_t)8192 * 2048 * 2;       // 33.6 MB
    float*  P      = (float*)p;  p += (size_t)16 * 64 * 4096 * 4;    // 16.8 MB
    __bf16* S2     = (__bf16*)p; p += (size_t)64 * 4096 * 2;         // 0.5 MB
    __bf16* Wf     = (__bf16*)p; p += (size_t)4 * 1024 * 1024 * 2;   // 8.4 MB
    __bf16* Weff   = (__bf16*)p; p += (size_t)4 * 1024 * 1024 * 2;   // 8.4 MB
    float*  r      = (float*)p;  p += (size_t)4 * 1024 * 4;          // 16 KB

    cvt_kv<<<24576, 256, 0, stream>>>(Wqkv, WkvB);
    cvt_bf16<<<12288, 256, 0, stream>>>(Wproj, WprojB, 3145728);
    wq_transpose<<<dim3(16, 16, 12), 256, 0, stream>>>(Wqkv, WqT);
    init_x<<<8192, 256, 0, stream>>>(x0, xPing, xF, 2097152);

    __bf16* xb[2] = { xPing, xPong };
    for (int i = 0; i < 12; ++i) {
        __bf16* xCur = xb[i & 1];
        __bf16* xNxt = xb[(i + 1) & 1];
        // kv = x @ Wkv^T + b_kv                         [8192,2048]
        gemm_bt<0><<<dim3(16, 64, 1), 256, 0, stream>>>(
            xCur, WkvB + (size_t)i * 2097152, bqkv + i * 3072 + 1024,
            kv, nullptr, 8192, 2048, 1024, 0, 0, 0, 0);
        // S2[bh][d1][d2] = scale * K^T V
        s_partial<<<dim3(64, 16), 256, 0, stream>>>(kv, P);
        s_reduce<<<256, 256, 0, stream>>>(P, S2);
        // Wf[b] = Wproj (x) S2  fold over d2
        wfold<<<64, 256, 0, stream>>>(WprojB + (size_t)i * 1048576, S2, Wf);
        // r[b] = bproj + bq . Wf[b]
        rvec<<<dim3(8, 4), 128, 0, stream>>>(bqkv + i * 3072, bproj + i * 1024, Wf, r);
        // Weff[b][n][c] = sum_k Wf[b][n][k] WqT[c][k]
        gemm_bt<2><<<dim3(8, 8, 4), 256, 0, stream>>>(
            Wf, WqT + (size_t)i * 1048576, nullptr, Weff, nullptr,
            1024, 1024, 1024, 1048576, 0, 0, 1048576);
        // x' = x + x @ Weff^T + r   (fp32 master + bf16 copy, per batch)
        gemm_bt<1><<<dim3(8, 16, 4), 256, 0, stream>>>(
            xCur, Weff, r, xNxt, xF,
            2048, 1024, 1024, 2097152, 1048576, 1024, 2097152);
    }
}

// Round 4
// 1441.004 us; speedup vs baseline: 1.6144x; 1.6144x over previous
//
#include <hip/hip_runtime.h>

typedef __attribute__((ext_vector_type(8))) __bf16 bf16x8;
typedef __attribute__((ext_vector_type(4))) __bf16 bf16x4;
typedef __attribute__((ext_vector_type(4))) float f32x4;
typedef __attribute__((ext_vector_type(4))) unsigned short u16x4;
typedef __attribute__((ext_vector_type(8))) int i32x8;

#define AS1 __attribute__((address_space(1)))
#define AS3 __attribute__((address_space(3)))

__device__ __forceinline__ void ld_g2l16(const void* g, void* l) {
    // 16B/lane direct global->LDS (m97). LDS dest is wave-uniform base.
    __builtin_amdgcn_global_load_lds((AS1 void*)g, (AS3 void*)l, 16, 0, 0);
}

__device__ __forceinline__ unsigned char fp8_of(float v) {
    return (unsigned char)(__builtin_amdgcn_cvt_pk_fp8_f32(v, v, 0, false) & 0xFF);
}

// ---------------------------------------------------------------------------
// MX-fp8 GEMM: C[m,n] = descale * sum_k A[m,k]*B[n,k] + bias[n]
// A:[M,K], B:[N,K] fp8-e4m3. 128x128 tile, BK=128, 4 waves 2x2, each wave
// 4x4 of 16x16x128 scaled-MFMA tiles (unit E8M0 scales = plain fp8 at 2x rate).
// MODE 0: bf16 out via LDS repack.  MODE 1: Cf += v (fp32 master), Cb = fp8(xv).
// ---------------------------------------------------------------------------
template<int MODE>
__global__ void gemm_fp8(const unsigned char* __restrict__ A,
                         const unsigned char* __restrict__ B,
                         const float* __restrict__ bias,
                         void* __restrict__ Cb, float* __restrict__ Cf,
                         int M, int N, int K, float descale)
{
    __shared__ __align__(32) unsigned char smem[34816]; // As 16K + Bs 16K; epi 128x136 bf16
    unsigned char* As = smem;
    unsigned char* Bs = smem + 16384;
    const int tid = threadIdx.x;
    const int wave = tid >> 6, lane = tid & 63;
    const int quad = lane >> 4, l15 = lane & 15;
    const int lrow = lane >> 3, lcol = lane & 7;
    const int m0 = blockIdx.y * 128, n0 = blockIdx.x * 128;
    const int wm = wave & 1, wn = wave >> 1;
    const unsigned char* Ab = A + (size_t)m0 * K;
    const unsigned char* Bb = B + (size_t)n0 * K;

    f32x4 acc[4][4] = {};

    for (int k0 = 0; k0 < K; k0 += 128) {
        __syncthreads();
        #pragma unroll
        for (int j = 0; j < 4; ++j) {
            const int chunk = wave * 4 + j;          // 16 chunks of 8 rows (128B each)
            const int row = chunk * 8 + lrow;
            ld_g2l16(Ab + (size_t)row * K + k0 + lcol * 16, &As[chunk * 1024]);
            ld_g2l16(Bb + (size_t)row * K + k0 + lcol * 16, &Bs[chunk * 1024]);
        }
        __syncthreads();
        i32x8 af[4], bfr[4];
        #pragma unroll
        for (int r = 0; r < 4; ++r)
            af[r] = *(const i32x8*)&As[(wm * 64 + r * 16 + l15) * 128 + quad * 32];
        #pragma unroll
        for (int c = 0; c < 4; ++c)
            bfr[c] = *(const i32x8*)&Bs[(wn * 64 + c * 16 + l15) * 128 + quad * 32];
        #pragma unroll
        for (int r = 0; r < 4; ++r)
            #pragma unroll
            for (int c = 0; c < 4; ++c)
                acc[r][c] = __builtin_amdgcn_mfma_scale_f32_16x16x128_f8f6f4(
                    af[r], bfr[c], acc[r][c], 0, 0, 0, 0x7F7F7F7F, 0, 0x7F7F7F7F);
    }

    // C/D layout (measured, shape-determined): col = lane&15, row = quad*4 + reg
    if (MODE == 0) {
        __syncthreads();
        __bf16 (*Cs)[136] = (__bf16(*)[136])smem;
        #pragma unroll
        for (int r = 0; r < 4; ++r)
            #pragma unroll
            for (int c = 0; c < 4; ++c) {
                const float bv = bias[n0 + wn * 64 + c * 16 + l15];
                #pragma unroll
                for (int e = 0; e < 4; ++e)
                    Cs[wm * 64 + r * 16 + quad * 4 + e][wn * 64 + c * 16 + l15] =
                        (__bf16)(acc[r][c][e] * descale + bv);
            }
        __syncthreads();
        __bf16* Cbb = (__bf16*)Cb;
        #pragma unroll
        for (int p = 0; p < 8; ++p) {
            const int i = p * 256 + tid;      // 2048 chunks of 16B
            const int row = i >> 4, ch = i & 15;
            *(bf16x8*)&Cbb[(size_t)(m0 + row) * N + n0 + ch * 8] =
                *(const bf16x8*)&Cs[row][ch * 8];
        }
    } else {
        unsigned char* Cb8 = (unsigned char*)Cb;
        #pragma unroll
        for (int r = 0; r < 4; ++r)
            #pragma unroll
            for (int c = 0; c < 4; ++c)
                #pragma unroll
                for (int e = 0; e < 4; ++e) {
                    const int m = m0 + wm * 64 + r * 16 + quad * 4 + e;
                    const int n = n0 + wn * 64 + c * 16 + l15;
                    const float v = acc[r][c][e] * descale + bias[n];
                    const size_t idx = (size_t)m * N + n;
                    const float xv = Cf[idx] + v;
                    Cf[idx] = xv;
                    Cb8[idx] = fp8_of(xv);
                }
    }
}

// ---------------------------------------------------------------------------
// s_partial: P[ch][bh][d1*... ] = sum_{t in chunk} K[t,d1]*V[t,d2]  (fp32)
// qkv layout [b,t,3072]: K at +1024, V at +2048.  Output layout [d2][d1]
// (d2 rows) to match y_kernel's B-fragment reads of St.
// ---------------------------------------------------------------------------
__global__ void s_partial(const __bf16* __restrict__ qkv, float* __restrict__ P)
{
    constexpr int CH = 128;
    __shared__ __align__(16) __bf16 Kt[64][CH + 8];
    __shared__ __align__(16) __bf16 Vt[64][CH + 8];
    const int bh = blockIdx.x, chb = blockIdx.y;
    const int b = bh >> 4, h = bh & 15;
    const int t0 = chb * CH;
    const int tid = threadIdx.x;
    const int wave = tid >> 6, lane = tid & 63;
    const int quad = lane >> 4, l15 = lane & 15;
    const __bf16* Kbase = qkv + (size_t)b * 2048 * 3072 + 1024 + h * 64;
    const __bf16* Vbase = Kbase + 1024;

    for (int i = tid; i < CH * 16; i += 256) {
        const int t = i >> 4, d4 = (i & 15) * 4;
        union { u16x4 u; __bf16 b[4]; } kv, vv;
        kv.u = *(const u16x4*)(Kbase + (size_t)(t0 + t) * 3072 + d4);
        vv.u = *(const u16x4*)(Vbase + (size_t)(t0 + t) * 3072 + d4);
        #pragma unroll
        for (int j = 0; j < 4; ++j) {
            Kt[d4 + j][t] = kv.b[j];
            Vt[d4 + j][t] = vv.b[j];
        }
    }
    __syncthreads();

    f32x4 acc[4] = {};
    #pragma unroll
    for (int s = 0; s < CH / 32; ++s) {
        const bf16x8 a = *(const bf16x8*)&Kt[wave * 16 + l15][s * 32 + quad * 8];  // m=d1
        #pragma unroll
        for (int c = 0; c < 4; ++c) {
            const bf16x8 bb = *(const bf16x8*)&Vt[c * 16 + l15][s * 32 + quad * 8]; // n=d2
            acc[c] = __builtin_amdgcn_mfma_f32_16x16x32_bf16(a, bb, acc[c], 0, 0, 0);
        }
    }

    // store as [d2][d1]: row = d2 = c*16+l15, col = d1 = wave*16+quad*4+e
    float* Pb = P + ((size_t)chb * 64 + bh) * 4096;
    #pragma unroll
    for (int c = 0; c < 4; ++c)
        *(f32x4*)&Pb[(size_t)(c * 16 + l15) * 64 + wave * 16 + quad * 4] = acc[c];
}

// s_reduce: St[bh][d2][d1] = 0.125 * sum_ch P[ch][bh][d2][d1]   (bf16)
__global__ void s_reduce(const float* __restrict__ P, __bf16* __restrict__ St)
{
    const int g = blockIdx.x * 256 + threadIdx.x;   // vec4 index, 65536 total
    f32x4 s = {};
    #pragma unroll
    for (int ch = 0; ch < 16; ++ch)
        s += *(const f32x4*)&P[(size_t)ch * 262144 + (size_t)g * 4];
    bf16x4 o;
    #pragma unroll
    for (int e = 0; e < 4; ++e) o[e] = (__bf16)(s[e] * 0.125f);
    *(bf16x4*)&St[(size_t)g * 4] = o;
}

// ---------------------------------------------------------------------------
// Y kernel: Y[b,t,h*64+d2] = 2^14 * sum_d1 Q[b,t,h,d1] * St[bh][d2][d1], fp8 out.
// ---------------------------------------------------------------------------
__global__ void y_kernel(const __bf16* __restrict__ qkv, const __bf16* __restrict__ St,
                         unsigned char* __restrict__ Y)
{
    __shared__ __align__(16) unsigned char smem[32768];  // staging 256x64 bf16; epi 256x72 fp8
    __bf16* Qs = (__bf16*)smem;
    const int bh = blockIdx.y, b = bh >> 4, h = bh & 15;
    const int t0 = blockIdx.x * 256;
    const int tid = threadIdx.x;
    const int wave = tid >> 6, lane = tid & 63;
    const int quad = lane >> 4, l15 = lane & 15;
    const int lrow = lane >> 3, lcol = lane & 7;
    const __bf16* Qb = qkv + ((size_t)b * 2048 + t0) * 3072 + h * 64;

    #pragma unroll
    for (int j = 0; j < 8; ++j) {
        const int chunk = wave * 8 + j;              // 32 chunks of 8 rows
        const int row = chunk * 8 + lrow;
        ld_g2l16(Qb + (size_t)row * 3072 + lcol * 8, &Qs[chunk * 512]);
    }

    f32x4 acc[4][4] = {};
    const __bf16* Sb = St + (size_t)bh * 4096;
    __syncthreads();
    #pragma unroll
    for (int s = 0; s < 2; ++s) {
        bf16x8 af[4], bfr[4];
        #pragma unroll
        for (int r = 0; r < 4; ++r)
            af[r] = *(const bf16x8*)&Qs[(wave * 64 + r * 16 + l15) * 64 + s * 32 + quad * 8];
        #pragma unroll
        for (int c = 0; c < 4; ++c)
            bfr[c] = *(const bf16x8*)&Sb[(size_t)(c * 16 + l15) * 64 + s * 32 + quad * 8];
        #pragma unroll
        for (int r = 0; r < 4; ++r)
            #pragma unroll
            for (int c = 0; c < 4; ++c)
                acc[r][c] = __builtin_amdgcn_mfma_f32_16x16x32_bf16(af[r], bfr[c], acc[r][c], 0, 0, 0);
    }

    __syncthreads();
    unsigned char (*Cs)[72] = (unsigned char(*)[72])smem;
    #pragma unroll
    for (int r = 0; r < 4; ++r)
        #pragma unroll
        for (int c = 0; c < 4; ++c)
            #pragma unroll
            for (int e = 0; e < 4; ++e)
                Cs[wave * 64 + r * 16 + quad * 4 + e][c * 16 + l15] =
                    fp8_of(acc[r][c][e] * 16384.0f);
    __syncthreads();
    #pragma unroll
    for (int p = 0; p < 4; ++p) {
        const int i = p * 256 + tid;                 // 1024 chunks of 16B
        const int row = i >> 2, ch = i & 3;
        *(uint4*)&Y[((size_t)b * 2048 + t0 + row) * 1024 + h * 64 + ch * 16] =
            *(const uint4*)&Cs[row][ch * 16];
    }
}

// ---------------------------------------------------------------------------
__global__ void cvt_fp8(const float* __restrict__ src, unsigned int* __restrict__ dst,
                        float scale, int n4)
{
    const int i = blockIdx.x * 256 + threadIdx.x;
    if (i >= n4) return;
    const float4 v = ((const float4*)src)[i];
    int w = __builtin_amdgcn_cvt_pk_fp8_f32(v.x * scale, v.y * scale, 0, false);
    w = __builtin_amdgcn_cvt_pk_fp8_f32(v.z * scale, v.w * scale, w, true);
    dst[i] = (unsigned int)w;
}

__global__ void init_x(const float* __restrict__ src, unsigned int* __restrict__ x8,
                       float* __restrict__ xF, int n4)
{
    const int i = blockIdx.x * 256 + threadIdx.x;
    if (i >= n4) return;
    const float4 v = ((const float4*)src)[i];
    ((float4*)xF)[i] = v;
    int w = __builtin_amdgcn_cvt_pk_fp8_f32(v.x, v.y, 0, false);
    w = __builtin_amdgcn_cvt_pk_fp8_f32(v.z, v.w, w, true);
    x8[i] = (unsigned int)w;
}

// ---------------------------------------------------------------------------
extern "C" void kernel_launch(void* const* d_in, const int* in_sizes, int n_in,
                              void* d_out, int out_size, void* d_ws, size_t ws_size,
                              hipStream_t stream)
{
    const float* x0    = (const float*)d_in[0];   // [4,2048,1024]
    const float* Wqkv  = (const float*)d_in[1];   // [12,3072,1024]
    const float* bqkv  = (const float*)d_in[2];   // [12,3072]
    const float* Wproj = (const float*)d_in[3];   // [12,1024,1024]
    const float* bproj = (const float*)d_in[4];   // [12,1024]
    float* xF = (float*)d_out;                    // fp32 x master lives in d_out

    char* p = (char*)d_ws;
    unsigned char* WqkvF8  = (unsigned char*)p; p += (size_t)12 * 3072 * 1024;  // 37.7 MB
    unsigned char* WprojF8 = (unsigned char*)p; p += (size_t)12 * 1024 * 1024;  // 12.6 MB
    unsigned char* xB      = (unsigned char*)p; p += (size_t)8192 * 1024;       //  8.4 MB
    __bf16* qkv = (__bf16*)p; p += (size_t)8192 * 3072 * 2;                     // 50.3 MB
    float*  P   = (float*)p;  p += (size_t)16 * 64 * 4096 * 4;                  // 16.8 MB
    __bf16* St  = (__bf16*)p; p += (size_t)64 * 4096 * 2;                       //  0.5 MB
    unsigned char* Y = (unsigned char*)p; p += (size_t)8192 * 1024;             //  8.4 MB

    const float SW = 4096.0f;             // weight fp8 scale 2^12
    const float D0 = 1.0f / 4096.0f;      // qkv descale: x(1) * W(2^12)
    const float D1 = 1.0f / 67108864.0f;  // proj descale: Y(2^14) * W(2^12) = 2^-26

    cvt_fp8<<<36864, 256, 0, stream>>>(Wqkv, (unsigned int*)WqkvF8, SW, 9437184);
    cvt_fp8<<<12288, 256, 0, stream>>>(Wproj, (unsigned int*)WprojF8, SW, 3145728);
    init_x<<<8192, 256, 0, stream>>>(x0, (unsigned int*)xB, xF, 2097152);

    for (int i = 0; i < 12; ++i) {
        // qkv = x @ Wqkv^T + bqkv                      [8192,3072] bf16
        gemm_fp8<0><<<dim3(24, 64), 256, 0, stream>>>(
            xB, WqkvF8 + (size_t)i * 3145728, bqkv + i * 3072,
            qkv, nullptr, 8192, 3072, 1024, D0);
        // St[bh][d2][d1] = scale * K^T V
        s_partial<<<dim3(64, 16), 256, 0, stream>>>(qkv, P);
        s_reduce<<<256, 256, 0, stream>>>(P, St);
        // Y = 2^14 * Q @ S                             [8192,1024] fp8
        y_kernel<<<dim3(8, 64), 256, 0, stream>>>(qkv, St, Y);
        // x = x + Y @ Wproj^T + bproj  (fp32 master + fp8 copy)
        gemm_fp8<1><<<dim3(8, 64), 256, 0, stream>>>(
            Y, WprojF8 + (size_t)i * 1048576, bproj + i * 1024,
            xB, xF, 8192, 1024, 1024, D1);
    }
}